// Round 2
// 383.042 us; speedup vs baseline: 1.0621x; 1.0621x over previous
//
#include <hip/hip_runtime.h>

// ReconstructionLoss: loss = mean(|masks - onehot(argmax_c(src_stft[:,:,:F,:]))|)
// Shapes: masks [16,512,1024,4] f32, src_stft [16,512,2048,4] f32, out = scalar f32.
// Memory-bound: 268 MB read -> ~43 us ideal at 6.3 TB/s.
//
// V2 changes vs 407 us baseline:
//  - no single-address atomicAdd (4096-block same-line atomic tail suspected as
//    the gap between ~85 us measured and ~45 us roofline): block partials go to
//    d_ws, a 1-block kernel reduces them. Also removes the d_out memset dispatch.
//  - grid = 2048 blocks = exactly device-resident (256 CU x 8 blocks), one
//    scheduling round, uniform tail, 16 groups/thread.
//  - unroll x4 with 8 clustered nontemporal 16B loads per batch (streamed-once
//    data; deeper MLP).

typedef float f32x4 __attribute__((ext_vector_type(4)));

#define F_SHIFT 10          // F = 1024 mask-groups per (b,t), power of 2
#define F_MASK  1023u

// src group index for mask group g: (bt << (F_SHIFT+1)) | f  ==  g + (g & ~F_MASK)
__device__ __forceinline__ unsigned int src_idx(unsigned int g) {
    return g + (g & ~F_MASK);
}

__device__ __forceinline__ float group_cost(f32x4 m, f32x4 t) {
    // first-max argmax over 4 (strict > keeps the first max, like jnp/torch)
    int   idx  = 0;
    float best = t.x;
    if (t.y > best) { best = t.y; idx = 1; }
    if (t.z > best) { best = t.z; idx = 2; }
    if (t.w > best) { best = t.w; idx = 3; }
    float s;
    s  = fabsf(m.x - (idx == 0 ? 1.0f : 0.0f));
    s += fabsf(m.y - (idx == 1 ? 1.0f : 0.0f));
    s += fabsf(m.z - (idx == 2 ? 1.0f : 0.0f));
    s += fabsf(m.w - (idx == 3 ? 1.0f : 0.0f));
    return s;
}

__global__ __launch_bounds__(256) void recon_loss_partial(
    const f32x4* __restrict__ masks,   // G groups of 4 floats
    const f32x4* __restrict__ src,     // per (b,t): F gt groups then F phase groups
    float* __restrict__ partials,      // [gridDim.x] block partial sums (d_ws)
    unsigned int G)
{
    const unsigned int nth = gridDim.x * blockDim.x;
    const unsigned int tid = blockIdx.x * blockDim.x + threadIdx.x;
    const unsigned int iters = G / nth;     // 16 for the target shape (exact)

    float acc = 0.0f;
    unsigned int i = 0;

    // main: batches of 4 groups, 8 independent 16B loads issued together
    for (; i + 4 <= iters; i += 4) {
        const unsigned int g0 = tid + (i    ) * nth;
        const unsigned int g1 = tid + (i + 1) * nth;
        const unsigned int g2 = tid + (i + 2) * nth;
        const unsigned int g3 = tid + (i + 3) * nth;

        const f32x4 m0 = __builtin_nontemporal_load(&masks[g0]);
        const f32x4 m1 = __builtin_nontemporal_load(&masks[g1]);
        const f32x4 m2 = __builtin_nontemporal_load(&masks[g2]);
        const f32x4 m3 = __builtin_nontemporal_load(&masks[g3]);
        const f32x4 t0 = __builtin_nontemporal_load(&src[src_idx(g0)]);
        const f32x4 t1 = __builtin_nontemporal_load(&src[src_idx(g1)]);
        const f32x4 t2 = __builtin_nontemporal_load(&src[src_idx(g2)]);
        const f32x4 t3 = __builtin_nontemporal_load(&src[src_idx(g3)]);

        acc += group_cost(m0, t0);
        acc += group_cost(m1, t1);
        acc += group_cost(m2, t2);
        acc += group_cost(m3, t3);
    }
    // tail: iters not multiple of 4 (not hit for the target shape)
    for (; i < iters; ++i) {
        const unsigned int g = tid + i * nth;
        acc += group_cost(__builtin_nontemporal_load(&masks[g]),
                          __builtin_nontemporal_load(&src[src_idx(g)]));
    }
    // remainder stripe: G not divisible by nth (not hit for the target shape)
    for (unsigned int g = tid + iters * nth; g < G; g += nth) {
        acc += group_cost(__builtin_nontemporal_load(&masks[g]),
                          __builtin_nontemporal_load(&src[src_idx(g)]));
    }

    // wave-64 butterfly reduce
    #pragma unroll
    for (int off = 32; off > 0; off >>= 1)
        acc += __shfl_down(acc, off, 64);

    __shared__ float wsum[4];              // 256 threads / 64 = 4 waves
    const int lane = threadIdx.x & 63;
    const int wave = threadIdx.x >> 6;
    if (lane == 0) wsum[wave] = acc;
    __syncthreads();

    if (threadIdx.x == 0)
        partials[blockIdx.x] = wsum[0] + wsum[1] + wsum[2] + wsum[3];
}

__global__ __launch_bounds__(256) void reduce_partials(
    const float* __restrict__ partials,
    float* __restrict__ out,
    unsigned int n, float inv_n)
{
    float acc = 0.0f;
    for (unsigned int i = threadIdx.x; i < n; i += 256)
        acc += partials[i];

    #pragma unroll
    for (int off = 32; off > 0; off >>= 1)
        acc += __shfl_down(acc, off, 64);

    __shared__ float wsum[4];
    const int lane = threadIdx.x & 63;
    const int wave = threadIdx.x >> 6;
    if (lane == 0) wsum[wave] = acc;
    __syncthreads();

    if (threadIdx.x == 0)
        out[0] = (wsum[0] + wsum[1] + wsum[2] + wsum[3]) * inv_n;   // plain store: no memset needed
}

extern "C" void kernel_launch(void* const* d_in, const int* in_sizes, int n_in,
                              void* d_out, int out_size, void* d_ws, size_t ws_size,
                              hipStream_t stream) {
    const f32x4* masks = (const f32x4*)d_in[0];
    const f32x4* src   = (const f32x4*)d_in[1];
    float* out      = (float*)d_out;
    float* partials = (float*)d_ws;        // 2048 floats = 8 KB of workspace

    const unsigned int n_mask_elems = (unsigned int)in_sizes[0];   // 33,554,432
    const unsigned int G = n_mask_elems / 4;                       // 8,388,608 groups
    const float inv_n = 1.0f / (float)n_mask_elems;

    const int block = 256;
    const int grid  = 2048;   // exactly resident: 256 CU x 8 blocks, 16 groups/thread

    recon_loss_partial<<<grid, block, 0, stream>>>(masks, src, partials, G);
    reduce_partials<<<1, block, 0, stream>>>(partials, out, (unsigned int)grid, inv_n);
}